// Round 7
// baseline (129.365 us; speedup 1.0000x reference)
//
#include <hip/hip_runtime.h>
#include <math.h>

#define NUM_EXPERTS 16
#define HIDDEN 1024
#define INTER 768
#define TOKENS 64
#define TOPK 2
#define NPAIRS (TOKENS*TOPK)   // 128
#define GRP 8                  // tokens per staged group (= lanes>>3)

__device__ __forceinline__ float dot4(float4 a, float4 b) {
    return a.x*b.x + a.y*b.y + a.z*b.z + a.w*b.w;
}

// Deterministic expert pair-list build: wave 0 ballots over pairs [0,64) and
// [64,128). List is sorted by pair index -> identical across all blocks.
__device__ inline void build_plist(const int* __restrict__ topk_ids, int e,
                                   int tid, int* s_plist, int* s_np) {
    if (tid < 64) {
        const int lane = tid;
        int m0 = (topk_ids[lane]      == e);
        int m1 = (topk_ids[lane + 64] == e);
        unsigned long long b0 = __ballot(m0);
        unsigned long long b1 = __ballot(m1);
        int n0 = __popcll(b0);
        unsigned long long below = (lane == 0) ? 0ull : ((1ull << lane) - 1ull);
        if (m0) s_plist[__popcll(b0 & below)]      = lane;
        if (m1) s_plist[n0 + __popcll(b1 & below)] = lane + 64;
        if (lane == 0) *s_np = n0 + __popcll(b1);
    }
    __syncthreads();
}

// ---------------------------------------------------------------------------
// Pass 1 (tokens-in-lanes): h[p][o] = silu(x·w1[e,o]) * (x·w3[e,o])
// grid = (INTER/4 = 192, 16 experts), block 256 = 4 waves, 1 row per wave.
// lane = tok*8 + kg: tok = lane>>3 (one of 8 staged tokens), kg = lane&7
// (K-slice: float4 indices q ≡ kg mod 8). Weights stream with 1-float4 live
// range (nothing held across the token loop -> no remat trap); each w-load
// instr = 128 B contiguous across the wave, fetched exactly once.
// x staged in LDS, tok-XOR swizzled: slot = (q&7)^tok -> even 8 lanes/slot.
// Reduce: 3 shfl_xor per acc over kg; gate & up in the SAME lane (no pairing).
// ---------------------------------------------------------------------------
__global__ __launch_bounds__(256) void moe_pass1(
    const float* __restrict__ x,        // [64][1024]
    const int*   __restrict__ topk_ids, // [128]
    const float* __restrict__ w13,      // [16][1536][1024]
    float*       __restrict__ h)        // [128][768]
{
    const int e    = blockIdx.y;
    const int tid  = threadIdx.x;
    const int wave = tid >> 6;
    const int lane = tid & 63;
    const int kg   = lane & 7;
    const int tok  = lane >> 3;         // 0..7

    const int row  = blockIdx.x * 4 + wave;

    __shared__ int    s_plist[NPAIRS];
    __shared__ int    s_np;
    __shared__ float4 s_x[GRP * 256];   // 32 KB, swizzled

    build_plist(topk_ids, e, tid, s_plist, &s_np);
    const int np = s_np;
    if (np == 0) return;

    const float4* w1row = (const float4*)(w13 + ((size_t)e * (2*INTER) + row) * HIDDEN);
    const float4* w3row = (const float4*)(w13 + ((size_t)e * (2*INTER) + INTER + row) * HIDDEN);

    for (int g = 0; g * GRP < np; ++g) {
        const int gnp = min(GRP, np - g * GRP);
        if (g) __syncthreads();                      // protect s_x reuse
        for (int idx = tid; idx < gnp * 256; idx += 256) {
            int tk = idx >> 8, q = idx & 255;
            int t  = s_plist[g*GRP + tk] >> 1;
            s_x[tk*256 + (q ^ tk)] = ((const float4*)(x + (size_t)t * HIDDEN))[q];
        }
        __syncthreads();

        float a1a = 0.f, a1b = 0.f, a3a = 0.f, a3b = 0.f;
        #pragma unroll
        for (int it = 0; it < 32; it += 2) {
            const int q0 = it*8 + kg;
            const int q1 = q0 + 8;
            float4 xv0 = s_x[tok*256 + (q0 ^ tok)];
            float4 xv1 = s_x[tok*256 + (q1 ^ tok)];
            float4 w10 = w1row[q0];
            float4 w30 = w3row[q0];
            float4 w11 = w1row[q1];
            float4 w31 = w3row[q1];
            a1a += dot4(w10, xv0);  a3a += dot4(w30, xv0);
            a1b += dot4(w11, xv1);  a3b += dot4(w31, xv1);
        }
        float acc1 = a1a + a1b;
        float acc3 = a3a + a3b;
        acc1 += __shfl_xor(acc1, 1, 64);
        acc1 += __shfl_xor(acc1, 2, 64);
        acc1 += __shfl_xor(acc1, 4, 64);
        acc3 += __shfl_xor(acc3, 1, 64);
        acc3 += __shfl_xor(acc3, 2, 64);
        acc3 += __shfl_xor(acc3, 4, 64);
        if (kg == 0 && tok < gnp) {
            int p = s_plist[g*GRP + tok];
            float gate = acc1 / (1.f + expf(-acc1));
            h[(size_t)p * INTER + row] = gate * acc3;
        }
    }
}

// ---------------------------------------------------------------------------
// Pass 2 (tokens-in-lanes): y[p][i] = sum_o h[p][o] * w2[e][i][o]
// grid = (HIDDEN/4 = 256, 16 experts), block 256 = 4 waves, 1 row per wave.
// Same template: 8 tok x 8 kg lanes; h staged in LDS swizzled; 24 float4
// per lane-slice (q = it*8+kg, it 0..23); 3 shfl_xor reduce.
// ---------------------------------------------------------------------------
__global__ __launch_bounds__(256) void moe_pass2(
    const int*   __restrict__ topk_ids, // [128]
    const float* __restrict__ w2,       // [16][1024][768]
    const float* __restrict__ h,        // [128][768]
    float*       __restrict__ y)        // [128][1024]
{
    const int e    = blockIdx.y;
    const int tid  = threadIdx.x;
    const int wave = tid >> 6;
    const int lane = tid & 63;
    const int kg   = lane & 7;
    const int tok  = lane >> 3;

    const int row  = blockIdx.x * 4 + wave;

    __shared__ int    s_plist[NPAIRS];
    __shared__ int    s_np;
    __shared__ float4 s_h[GRP * 192];   // 24 KB, swizzled

    build_plist(topk_ids, e, tid, s_plist, &s_np);
    const int np = s_np;
    if (np == 0) return;

    const float4* wrow = (const float4*)(w2 + ((size_t)e * HIDDEN + row) * INTER);

    for (int g = 0; g * GRP < np; ++g) {
        const int gnp = min(GRP, np - g * GRP);
        if (g) __syncthreads();
        for (int idx = tid; idx < gnp * 192; idx += 256) {
            int tk = idx / 192, q = idx % 192;
            int p  = s_plist[g*GRP + tk];
            s_h[tk*192 + (q ^ tk)] = ((const float4*)(h + (size_t)p * INTER))[q];
        }
        __syncthreads();

        float aa = 0.f, ab = 0.f;
        #pragma unroll
        for (int it = 0; it < 24; it += 2) {
            const int q0 = it*8 + kg;
            const int q1 = q0 + 8;
            float4 hv0 = s_h[tok*192 + (q0 ^ tok)];
            float4 hv1 = s_h[tok*192 + (q1 ^ tok)];
            float4 w0  = wrow[q0];
            float4 w1  = wrow[q1];
            aa += dot4(w0, hv0);
            ab += dot4(w1, hv1);
        }
        float acc = aa + ab;
        acc += __shfl_xor(acc, 1, 64);
        acc += __shfl_xor(acc, 2, 64);
        acc += __shfl_xor(acc, 4, 64);
        if (kg == 0 && tok < gnp) {
            int p = s_plist[g*GRP + tok];
            y[(size_t)p * HIDDEN + row] = acc;
        }
    }
}

// ---------------------------------------------------------------------------
// Pass 3: out[t][i] = tw[t][0]*y[2t][i] + tw[t][1]*y[2t+1][i]
// ---------------------------------------------------------------------------
__global__ __launch_bounds__(256) void moe_combine(
    const float* __restrict__ tw,   // [64][2]
    const float* __restrict__ y,    // [128][1024]
    float*       __restrict__ out)  // [64][1024]
{
    int idx = blockIdx.x * 256 + threadIdx.x;       // 16384 float4 slots
    int t = idx / (HIDDEN/4);
    int c = idx % (HIDDEN/4);
    float w0 = tw[t*2+0], w1 = tw[t*2+1];
    float4 a = *(const float4*)(y + (size_t)(2*t  )*HIDDEN + c*4);
    float4 b = *(const float4*)(y + (size_t)(2*t+1)*HIDDEN + c*4);
    float4 o;
    o.x = w0*a.x + w1*b.x;
    o.y = w0*a.y + w1*b.y;
    o.z = w0*a.z + w1*b.z;
    o.w = w0*a.w + w1*b.w;
    *(float4*)(out + (size_t)t*HIDDEN + c*4) = o;
}

extern "C" void kernel_launch(void* const* d_in, const int* in_sizes, int n_in,
                              void* d_out, int out_size, void* d_ws, size_t ws_size,
                              hipStream_t stream) {
    const float* x   = (const float*)d_in[0];
    const int*   ids = (const int*)  d_in[1];
    const float* tw  = (const float*)d_in[2];
    const float* w13 = (const float*)d_in[3];
    const float* w2  = (const float*)d_in[4];
    float* out = (float*)d_out;

    float* h = (float*)d_ws;                 // 128*768  floats
    float* y = h + (size_t)NPAIRS * INTER;   // 128*1024 floats

    dim3 g1(INTER/4, NUM_EXPERTS);     // (192, 16)
    moe_pass1<<<g1, 256, 0, stream>>>(x, ids, w13, h);

    dim3 g2(HIDDEN/4, NUM_EXPERTS);    // (256, 16)
    moe_pass2<<<g2, 256, 0, stream>>>(ids, w2, h, y);

    moe_combine<<<(TOKENS*HIDDEN/4)/256, 256, 0, stream>>>(tw, y, out);
}

// Round 8
// 57.575 us; speedup vs baseline: 2.2469x; 2.2469x over previous
//
#include <hip/hip_runtime.h>
#include <math.h>

#define NUM_EXPERTS 16
#define HIDDEN 1024
#define INTER 768
#define TOKENS 64
#define TOPK 2
#define NPAIRS (TOKENS*TOPK)   // 128
#define GRP 8                  // tokens staged per group

__device__ __forceinline__ float dot4(float4 a, float4 b) {
    return a.x*b.x + a.y*b.y + a.z*b.z + a.w*b.w;
}

// Deterministic expert pair-list build: wave 0 ballots over pairs [0,64) and
// [64,128). List is sorted by pair index -> identical across all blocks.
__device__ inline void build_plist(const int* __restrict__ topk_ids, int e,
                                   int tid, int* s_plist, int* s_np) {
    if (tid < 64) {
        const int lane = tid;
        int m0 = (topk_ids[lane]      == e);
        int m1 = (topk_ids[lane + 64] == e);
        unsigned long long b0 = __ballot(m0);
        unsigned long long b1 = __ballot(m1);
        int n0 = __popcll(b0);
        unsigned long long below = (lane == 0) ? 0ull : ((1ull << lane) - 1ull);
        if (m0) s_plist[__popcll(b0 & below)]      = lane;
        if (m1) s_plist[n0 + __popcll(b1 & below)] = lane + 64;
        if (lane == 0) *s_np = n0 + __popcll(b1);
    }
    __syncthreads();
}

// ---------------------------------------------------------------------------
// Pass 1: h[p][o] = silu(x[t]·w1[e,o,:]) * (x[t]·w3[e,o,:])
// grid = (INTER/8 = 96, 16 experts), block = 256 (4 waves).
// Wave = 4 groups of 16 lanes: grp = (rowoff<<1)|mat ->
//   g0: w1·rowA  g1: w3·rowA  g2: w1·rowB  g3: w3·rowB
// Lane holds its row's 16-float4 K-slice in regs ACROSS the 8-token LDS loop
// (R3-proven residency scope: VGPR=68 there). All 4 groups read the same
// s_x address per instruction -> 4-way LDS multicast (free).
// Reduce: 4 shfl_xor within 16 lanes + 1 pairing shfl_xor(16) -> 2 outputs.
// ---------------------------------------------------------------------------
__global__ __launch_bounds__(256) void moe_pass1(
    const float* __restrict__ x,        // [64][1024]
    const int*   __restrict__ topk_ids, // [128]
    const float* __restrict__ w13,      // [16][1536][1024]
    float*       __restrict__ h)        // [128][768]
{
    const int e    = blockIdx.y;
    const int tid  = threadIdx.x;
    const int wave = tid >> 6;
    const int lane = tid & 63;
    const int grp  = lane >> 4;         // 0..3
    const int l16  = lane & 15;
    const int row  = blockIdx.x * 8 + wave * 2 + (grp >> 1);
    const int mat  = grp & 1;           // 0 = w1, 1 = w3

    __shared__ int    s_plist[NPAIRS];
    __shared__ int    s_np;
    __shared__ float4 s_x[GRP][HIDDEN/4];   // 32 KB

    build_plist(topk_ids, e, tid, s_plist, &s_np);
    const int np = s_np;
    if (np == 0) return;

    const float4* wrow = (const float4*)w13
        + ((size_t)e * (2*INTER) + (size_t)mat * INTER + row) * (HIDDEN/4) + l16;

    float4 w[16];
    #pragma unroll
    for (int j = 0; j < 16; ++j) w[j] = wrow[j * 16];

    for (int g = 0; g * GRP < np; ++g) {
        const int gnp = min(GRP, np - g * GRP);
        if (g) __syncthreads();
        for (int idx = tid; idx < gnp * (HIDDEN/4); idx += 256) {
            int tk = idx >> 8, q = idx & 255;
            int t  = s_plist[g*GRP + tk] >> 1;
            s_x[tk][q] = ((const float4*)x)[(size_t)t * (HIDDEN/4) + q];
        }
        __syncthreads();

        #pragma unroll
        for (int tau = 0; tau < GRP; ++tau) {
            float a0 = 0.f, a1 = 0.f, a2 = 0.f, a3 = 0.f;
            #pragma unroll
            for (int j = 0; j < 16; j += 4) {
                a0 += dot4(w[j+0], s_x[tau][l16 + (j+0)*16]);
                a1 += dot4(w[j+1], s_x[tau][l16 + (j+1)*16]);
                a2 += dot4(w[j+2], s_x[tau][l16 + (j+2)*16]);
                a3 += dot4(w[j+3], s_x[tau][l16 + (j+3)*16]);
            }
            float acc = (a0 + a1) + (a2 + a3);
            acc += __shfl_xor(acc, 1, 64);
            acc += __shfl_xor(acc, 2, 64);
            acc += __shfl_xor(acc, 4, 64);
            acc += __shfl_xor(acc, 8, 64);
            float other = __shfl_xor(acc, 16, 64);   // pairs w1 <-> w3
            if (mat == 0 && l16 == 0 && tau < gnp) {
                int p = s_plist[g*GRP + tau];
                float gate = acc / (1.f + expf(-acc));
                h[(size_t)p * INTER + row] = gate * other;
            }
        }
    }
}

// ---------------------------------------------------------------------------
// Pass 2: y[p][i] = sum_o h[p][o] * w2[e][i][o]
// Same template. grid = (HIDDEN/16 = 64, 16 experts), block = 256.
// Wave = 4 groups x 16 lanes, one row per group; lane holds 12 float4
// (48 regs) across the 8-token LDS loop. 4 shfl_xor per output.
// ---------------------------------------------------------------------------
__global__ __launch_bounds__(256) void moe_pass2(
    const int*   __restrict__ topk_ids, // [128]
    const float* __restrict__ w2,       // [16][1024][768]
    const float* __restrict__ h,        // [128][768]
    float*       __restrict__ y)        // [128][1024]
{
    const int e    = blockIdx.y;
    const int tid  = threadIdx.x;
    const int wave = tid >> 6;
    const int lane = tid & 63;
    const int grp  = lane >> 4;
    const int l16  = lane & 15;
    const int row  = blockIdx.x * 16 + wave * 4 + grp;

    __shared__ int    s_plist[NPAIRS];
    __shared__ int    s_np;
    __shared__ float4 s_h[GRP][INTER/4];    // 24 KB

    build_plist(topk_ids, e, tid, s_plist, &s_np);
    const int np = s_np;
    if (np == 0) return;

    const float4* wrow = (const float4*)w2
        + ((size_t)e * HIDDEN + row) * (INTER/4) + l16;

    float4 w[12];
    #pragma unroll
    for (int j = 0; j < 12; ++j) w[j] = wrow[j * 16];

    for (int g = 0; g * GRP < np; ++g) {
        const int gnp = min(GRP, np - g * GRP);
        if (g) __syncthreads();
        for (int idx = tid; idx < gnp * (INTER/4); idx += 256) {
            int tk = idx / (INTER/4), q = idx % (INTER/4);
            int p  = s_plist[g*GRP + tk];
            s_h[tk][q] = ((const float4*)h)[(size_t)p * (INTER/4) + q];
        }
        __syncthreads();

        #pragma unroll
        for (int tau = 0; tau < GRP; ++tau) {
            float a0 = 0.f, a1 = 0.f, a2 = 0.f, a3 = 0.f;
            #pragma unroll
            for (int j = 0; j < 12; j += 4) {
                a0 += dot4(w[j+0], s_h[tau][l16 + (j+0)*16]);
                a1 += dot4(w[j+1], s_h[tau][l16 + (j+1)*16]);
                a2 += dot4(w[j+2], s_h[tau][l16 + (j+2)*16]);
                a3 += dot4(w[j+3], s_h[tau][l16 + (j+3)*16]);
            }
            float acc = (a0 + a1) + (a2 + a3);
            acc += __shfl_xor(acc, 1, 64);
            acc += __shfl_xor(acc, 2, 64);
            acc += __shfl_xor(acc, 4, 64);
            acc += __shfl_xor(acc, 8, 64);
            if (l16 == 0 && tau < gnp) {
                int p = s_plist[g*GRP + tau];
                y[(size_t)p * HIDDEN + row] = acc;
            }
        }
    }
}

// ---------------------------------------------------------------------------
// Pass 3: out[t][i] = tw[t][0]*y[2t][i] + tw[t][1]*y[2t+1][i]
// ---------------------------------------------------------------------------
__global__ __launch_bounds__(256) void moe_combine(
    const float* __restrict__ tw,   // [64][2]
    const float* __restrict__ y,    // [128][1024]
    float*       __restrict__ out)  // [64][1024]
{
    int idx = blockIdx.x * 256 + threadIdx.x;       // 16384 float4 slots
    int t = idx / (HIDDEN/4);
    int c = idx % (HIDDEN/4);
    float w0 = tw[t*2+0], w1 = tw[t*2+1];
    float4 a = *(const float4*)(y + (size_t)(2*t  )*HIDDEN + c*4);
    float4 b = *(const float4*)(y + (size_t)(2*t+1)*HIDDEN + c*4);
    float4 o;
    o.x = w0*a.x + w1*b.x;
    o.y = w0*a.y + w1*b.y;
    o.z = w0*a.z + w1*b.z;
    o.w = w0*a.w + w1*b.w;
    *(float4*)(out + (size_t)t*HIDDEN + c*4) = o;
}

extern "C" void kernel_launch(void* const* d_in, const int* in_sizes, int n_in,
                              void* d_out, int out_size, void* d_ws, size_t ws_size,
                              hipStream_t stream) {
    const float* x   = (const float*)d_in[0];
    const int*   ids = (const int*)  d_in[1];
    const float* tw  = (const float*)d_in[2];
    const float* w13 = (const float*)d_in[3];
    const float* w2  = (const float*)d_in[4];
    float* out = (float*)d_out;

    float* h = (float*)d_ws;                 // 128*768  floats
    float* y = h + (size_t)NPAIRS * INTER;   // 128*1024 floats

    dim3 g1(INTER/8, NUM_EXPERTS);     // (96, 16)
    moe_pass1<<<g1, 256, 0, stream>>>(x, ids, w13, h);

    dim3 g2(HIDDEN/16, NUM_EXPERTS);   // (64, 16)
    moe_pass2<<<g2, 256, 0, stream>>>(ids, w2, h, y);

    moe_combine<<<(TOKENS*HIDDEN/4)/256, 256, 0, stream>>>(tw, y, out);
}

// Round 9
// 57.330 us; speedup vs baseline: 2.2565x; 1.0043x over previous
//
#include <hip/hip_runtime.h>
#include <math.h>

#define NUM_EXPERTS 16
#define HIDDEN 1024
#define INTER 768
#define TOKENS 64
#define TOPK 2
#define NPAIRS (TOKENS*TOPK)   // 128
#define GRP 8                  // tokens staged per group

__device__ __forceinline__ float dot4(float4 a, float4 b) {
    return a.x*b.x + a.y*b.y + a.z*b.z + a.w*b.w;
}

// Deterministic expert pair-list build: wave 0 ballots over pairs [0,64) and
// [64,128). List is sorted by pair index -> identical across all blocks.
__device__ inline void build_plist(const int* __restrict__ topk_ids, int e,
                                   int tid, int* s_plist, int* s_np) {
    if (tid < 64) {
        const int lane = tid;
        int m0 = (topk_ids[lane]      == e);
        int m1 = (topk_ids[lane + 64] == e);
        unsigned long long b0 = __ballot(m0);
        unsigned long long b1 = __ballot(m1);
        int n0 = __popcll(b0);
        unsigned long long below = (lane == 0) ? 0ull : ((1ull << lane) - 1ull);
        if (m0) s_plist[__popcll(b0 & below)]      = lane;
        if (m1) s_plist[n0 + __popcll(b1 & below)] = lane + 64;
        if (lane == 0) *s_np = n0 + __popcll(b1);
    }
    __syncthreads();
}

// ---------------------------------------------------------------------------
// Pass 1: h[p][o] = silu(x[t]·w1[e,o,:]) * (x[t]·w3[e,o,:])
// grid = (INTER/8 = 96, 16 experts), block = 256 (4 waves).
// Wave = 4 groups of 16 lanes: g0: w1·rowA  g1: w3·rowA  g2: w1·rowB  g3: w3·rowB
// Lane holds its row's 16-float4 K-slice in regs across the 8-token LDS loop.
// __launch_bounds__(256,4): LDS (33KB) caps us at 4 blocks/CU = 4 waves/SIMD
// anyway -> grant the allocator 512/4 = 128 VGPRs so w[16] (64 regs) STAYS
// RESIDENT. (R5/R6/R8 evidence: default budget 52 -> remat, 8x weight re-read.)
// Reduce: 4 shfl_xor within 16 lanes + 1 pairing shfl_xor(16) -> 2 outputs.
// ---------------------------------------------------------------------------
__global__ __launch_bounds__(256, 4) void moe_pass1(
    const float* __restrict__ x,        // [64][1024]
    const int*   __restrict__ topk_ids, // [128]
    const float* __restrict__ w13,      // [16][1536][1024]
    float*       __restrict__ h)        // [128][768]
{
    const int e    = blockIdx.y;
    const int tid  = threadIdx.x;
    const int wave = tid >> 6;
    const int lane = tid & 63;
    const int grp  = lane >> 4;         // 0..3
    const int l16  = lane & 15;
    const int row  = blockIdx.x * 8 + wave * 2 + (grp >> 1);
    const int mat  = grp & 1;           // 0 = w1, 1 = w3

    __shared__ int    s_plist[NPAIRS];
    __shared__ int    s_np;
    __shared__ float4 s_x[GRP][HIDDEN/4];   // 32 KB

    build_plist(topk_ids, e, tid, s_plist, &s_np);
    const int np = s_np;
    if (np == 0) return;

    const float4* wrow = (const float4*)w13
        + ((size_t)e * (2*INTER) + (size_t)mat * INTER + row) * (HIDDEN/4) + l16;

    float4 w[16];
    #pragma unroll
    for (int j = 0; j < 16; ++j) w[j] = wrow[j * 16];

    for (int g = 0; g * GRP < np; ++g) {
        const int gnp = min(GRP, np - g * GRP);
        if (g) __syncthreads();
        for (int idx = tid; idx < gnp * (HIDDEN/4); idx += 256) {
            int tk = idx >> 8, q = idx & 255;
            int t  = s_plist[g*GRP + tk] >> 1;
            s_x[tk][q] = ((const float4*)x)[(size_t)t * (HIDDEN/4) + q];
        }
        __syncthreads();

        #pragma unroll
        for (int tau = 0; tau < GRP; ++tau) {
            float a0 = 0.f, a1 = 0.f, a2 = 0.f, a3 = 0.f;
            #pragma unroll
            for (int j = 0; j < 16; j += 4) {
                a0 += dot4(w[j+0], s_x[tau][l16 + (j+0)*16]);
                a1 += dot4(w[j+1], s_x[tau][l16 + (j+1)*16]);
                a2 += dot4(w[j+2], s_x[tau][l16 + (j+2)*16]);
                a3 += dot4(w[j+3], s_x[tau][l16 + (j+3)*16]);
            }
            float acc = (a0 + a1) + (a2 + a3);
            acc += __shfl_xor(acc, 1, 64);
            acc += __shfl_xor(acc, 2, 64);
            acc += __shfl_xor(acc, 4, 64);
            acc += __shfl_xor(acc, 8, 64);
            float other = __shfl_xor(acc, 16, 64);   // pairs w1 <-> w3
            if (mat == 0 && l16 == 0 && tau < gnp) {
                int p = s_plist[g*GRP + tau];
                float gate = acc / (1.f + expf(-acc));
                h[(size_t)p * INTER + row] = gate * other;
            }
        }
    }
}

// ---------------------------------------------------------------------------
// Pass 2: y[p][i] = sum_o h[p][o] * w2[e][i][o]
// Same template. grid = (HIDDEN/16 = 64, 16 experts), block = 256.
// Wave = 4 groups x 16 lanes, one row per group; lane holds 12 float4
// (48 regs) across the 8-token LDS loop. __launch_bounds__(256,4) for the
// same allocator-budget reason (LDS caps at 4-5 blocks/CU regardless).
// ---------------------------------------------------------------------------
__global__ __launch_bounds__(256, 4) void moe_pass2(
    const int*   __restrict__ topk_ids, // [128]
    const float* __restrict__ w2,       // [16][1024][768]
    const float* __restrict__ h,        // [128][768]
    float*       __restrict__ y)        // [128][1024]
{
    const int e    = blockIdx.y;
    const int tid  = threadIdx.x;
    const int wave = tid >> 6;
    const int lane = tid & 63;
    const int grp  = lane >> 4;
    const int l16  = lane & 15;
    const int row  = blockIdx.x * 16 + wave * 4 + grp;

    __shared__ int    s_plist[NPAIRS];
    __shared__ int    s_np;
    __shared__ float4 s_h[GRP][INTER/4];    // 24 KB

    build_plist(topk_ids, e, tid, s_plist, &s_np);
    const int np = s_np;
    if (np == 0) return;

    const float4* wrow = (const float4*)w2
        + ((size_t)e * HIDDEN + row) * (INTER/4) + l16;

    float4 w[12];
    #pragma unroll
    for (int j = 0; j < 12; ++j) w[j] = wrow[j * 16];

    for (int g = 0; g * GRP < np; ++g) {
        const int gnp = min(GRP, np - g * GRP);
        if (g) __syncthreads();
        for (int idx = tid; idx < gnp * (INTER/4); idx += 256) {
            int tk = idx / (INTER/4), q = idx % (INTER/4);
            int p  = s_plist[g*GRP + tk];
            s_h[tk][q] = ((const float4*)h)[(size_t)p * (INTER/4) + q];
        }
        __syncthreads();

        #pragma unroll
        for (int tau = 0; tau < GRP; ++tau) {
            float a0 = 0.f, a1 = 0.f, a2 = 0.f, a3 = 0.f;
            #pragma unroll
            for (int j = 0; j < 12; j += 4) {
                a0 += dot4(w[j+0], s_h[tau][l16 + (j+0)*16]);
                a1 += dot4(w[j+1], s_h[tau][l16 + (j+1)*16]);
                a2 += dot4(w[j+2], s_h[tau][l16 + (j+2)*16]);
                a3 += dot4(w[j+3], s_h[tau][l16 + (j+3)*16]);
            }
            float acc = (a0 + a1) + (a2 + a3);
            acc += __shfl_xor(acc, 1, 64);
            acc += __shfl_xor(acc, 2, 64);
            acc += __shfl_xor(acc, 4, 64);
            acc += __shfl_xor(acc, 8, 64);
            if (l16 == 0 && tau < gnp) {
                int p = s_plist[g*GRP + tau];
                y[(size_t)p * HIDDEN + row] = acc;
            }
        }
    }
}

// ---------------------------------------------------------------------------
// Pass 3: out[t][i] = tw[t][0]*y[2t][i] + tw[t][1]*y[2t+1][i]
// ---------------------------------------------------------------------------
__global__ __launch_bounds__(256) void moe_combine(
    const float* __restrict__ tw,   // [64][2]
    const float* __restrict__ y,    // [128][1024]
    float*       __restrict__ out)  // [64][1024]
{
    int idx = blockIdx.x * 256 + threadIdx.x;       // 16384 float4 slots
    int t = idx / (HIDDEN/4);
    int c = idx % (HIDDEN/4);
    float w0 = tw[t*2+0], w1 = tw[t*2+1];
    float4 a = *(const float4*)(y + (size_t)(2*t  )*HIDDEN + c*4);
    float4 b = *(const float4*)(y + (size_t)(2*t+1)*HIDDEN + c*4);
    float4 o;
    o.x = w0*a.x + w1*b.x;
    o.y = w0*a.y + w1*b.y;
    o.z = w0*a.z + w1*b.z;
    o.w = w0*a.w + w1*b.w;
    *(float4*)(out + (size_t)t*HIDDEN + c*4) = o;
}

extern "C" void kernel_launch(void* const* d_in, const int* in_sizes, int n_in,
                              void* d_out, int out_size, void* d_ws, size_t ws_size,
                              hipStream_t stream) {
    const float* x   = (const float*)d_in[0];
    const int*   ids = (const int*)  d_in[1];
    const float* tw  = (const float*)d_in[2];
    const float* w13 = (const float*)d_in[3];
    const float* w2  = (const float*)d_in[4];
    float* out = (float*)d_out;

    float* h = (float*)d_ws;                 // 128*768  floats
    float* y = h + (size_t)NPAIRS * INTER;   // 128*1024 floats

    dim3 g1(INTER/8, NUM_EXPERTS);     // (96, 16)
    moe_pass1<<<g1, 256, 0, stream>>>(x, ids, w13, h);

    dim3 g2(HIDDEN/16, NUM_EXPERTS);   // (64, 16)
    moe_pass2<<<g2, 256, 0, stream>>>(ids, w2, h, y);

    moe_combine<<<(TOKENS*HIDDEN/4)/256, 256, 0, stream>>>(tw, y, out);
}